// Round 1
// baseline (174.941 us; speedup 1.0000x reference)
//
#include <hip/hip_runtime.h>
#include <hip/hip_bf16.h>

#define B_ 16
#define SQ_ 2048
#define SK_ 2048
#define D_ 64
#define DV_ 64
#define INV_KEEP 1.1111111f  /* 1/(1-0.1) */

typedef float f4 __attribute__((ext_vector_type(4)));
typedef __bf16 bf16x8 __attribute__((ext_vector_type(8)));
typedef unsigned int u32;
typedef unsigned int u32x4 __attribute__((ext_vector_type(4)));
typedef unsigned short u16x4 __attribute__((ext_vector_type(4)));

// manual f32 -> bf16 RNE (branchless, no NaN inputs here)
static __device__ __forceinline__ unsigned short bf16u(float f) {
    u32 u = __builtin_bit_cast(u32, f);
    u += 0x7fffu + ((u >> 16) & 1u);
    return (unsigned short)(u >> 16);
}
static __device__ __forceinline__ u32 pk2(float lo, float hi) {
    return (u32)bf16u(lo) | ((u32)bf16u(hi) << 16);
}

// ---------------- prep kernel 1: K f32 -> bf16 row-major ----------------
__global__ __launch_bounds__(256) void cast_bf16_k(const float* __restrict__ X,
                                                   unsigned short* __restrict__ Y) {
    size_t i = ((size_t)blockIdx.x * 256 + threadIdx.x) * 4;
    f4 x = *(const f4*)(X + i);
    u16x4 u;
    u.x = bf16u(x.x); u.y = bf16u(x.y); u.z = bf16u(x.z); u.w = bf16u(x.w);
    *(u16x4*)(Y + i) = u;
}

// ---------------- prep kernel 2: V f32 [b][k][v] -> bf16 Vt [b][v][k] ----------------
__global__ __launch_bounds__(256) void transpose_v(const float* __restrict__ V,
                                                   unsigned short* __restrict__ Vt) {
    __shared__ float tile[64][68];
    int b  = blockIdx.x >> 5;
    int k0 = (blockIdx.x & 31) << 6;
    int t  = threadIdx.x;
    int kk = t >> 4, v4 = (t & 15) * 4;
#pragma unroll
    for (int i = 0; i < 4; ++i) {
        f4 x = *(const f4*)(V + ((size_t)(b * SK_ + k0 + kk + i * 16)) * DV_ + v4);
        *(f4*)&tile[kk + i * 16][v4] = x;
    }
    __syncthreads();
    int v = t >> 2, kc = (t & 3) << 4;
    unsigned short* dst = Vt + ((size_t)(b * DV_ + v)) * SK_ + k0 + kc;
#pragma unroll
    for (int j4 = 0; j4 < 4; ++j4) {
        u16x4 u;
        u.x = bf16u(tile[kc + j4 * 4 + 0][v]);
        u.y = bf16u(tile[kc + j4 * 4 + 1][v]);
        u.z = bf16u(tile[kc + j4 * 4 + 2][v]);
        u.w = bf16u(tile[kc + j4 * 4 + 3][v]);
        *(u16x4*)(dst + j4 * 4) = u;
    }
}

// ---------------- main fused attention kernel ----------------
// 1 wave = 16 q-rows. Swapped QK^T (S^T = K·Q^T), online softmax, dropout, PV.
__global__ __launch_bounds__(256) void attn_main(const float* __restrict__ Q,
                                                 const unsigned short* __restrict__ Kb,
                                                 const unsigned short* __restrict__ Vt,
                                                 const float* __restrict__ mask,
                                                 float* __restrict__ out) {
    // XCD swizzle: 512 blocks, 8 XCDs -> each XCD gets 64 contiguous blocks (2 batches)
    int bswz = (blockIdx.x & 7) * 64 + (blockIdx.x >> 3);
    int w    = bswz * 4 + (threadIdx.x >> 6);
    int b    = w >> 7;            // 128 q-strips per batch
    int q0   = (w & 127) << 4;
    int lane = threadIdx.x & 63;
    int g = lane >> 4, c = lane & 15;

    // Q fragments (B-operand of swapped QK^T): lane reads Q[q0+c][h*32+8g .. +8], scale 1/8 folded
    bf16x8 qf[2];
    {
        const float* qp = Q + ((size_t)(b * SQ_ + q0 + c)) * D_ + 8 * g;
#pragma unroll
        for (int h = 0; h < 2; ++h) {
            f4 a  = *(const f4*)(qp + h * 32);
            f4 bq = *(const f4*)(qp + h * 32 + 4);
            u32x4 wq;
            wq[0] = pk2(a.x * 0.125f, a.y * 0.125f);
            wq[1] = pk2(a.z * 0.125f, a.w * 0.125f);
            wq[2] = pk2(bq.x * 0.125f, bq.y * 0.125f);
            wq[3] = pk2(bq.z * 0.125f, bq.w * 0.125f);
            qf[h] = __builtin_bit_cast(bf16x8, wq);
        }
    }

    const unsigned short* kbase = Kb + ((size_t)(b * SK_ + c)) * D_ + 8 * g;   // + (k0+16t)*64 + 32h
    const unsigned short* vbase = Vt + ((size_t)(b * DV_ + c)) * SK_ + 8 * g;  // + vb*16*SK + k0
    const float* mbase = mask + ((size_t)(b * SQ_ + q0 + c)) * SK_ + 4 * g;    // + k0 + 16t

    f4 acc[4];
#pragma unroll
    for (int vb = 0; vb < 4; ++vb) acc[vb] = (f4){0.f, 0.f, 0.f, 0.f};
    float m_run = -__builtin_inff();
    float l_run = 0.f;

    auto load_tile = [&](int k32, u32x4 (&kf)[2][2], u32x4 (&vf)[4], f4 (&mk)[2]) {
#pragma unroll
        for (int t = 0; t < 2; ++t)
#pragma unroll
            for (int h = 0; h < 2; ++h)
                kf[t][h] = *(const u32x4*)(kbase + (size_t)(k32 + 16 * t) * D_ + 32 * h);
#pragma unroll
        for (int vb = 0; vb < 4; ++vb)
            vf[vb] = *(const u32x4*)(vbase + (size_t)vb * 16 * SK_ + k32);
#pragma unroll
        for (int t = 0; t < 2; ++t)
            mk[t] = __builtin_nontemporal_load((const f4*)(mbase + k32 + 16 * t));
    };

    auto compute_tile = [&](u32x4 (&kf)[2][2], u32x4 (&vf)[4], f4 (&mk)[2]) {
        // QK^T: S^T tiles [16k][16q], row = k_local = 4g+r (+16t), col = q = c
        f4 st[2];
#pragma unroll
        for (int t = 0; t < 2; ++t) {
            st[t] = (f4){0.f, 0.f, 0.f, 0.f};
            st[t] = __builtin_amdgcn_mfma_f32_16x16x32_bf16(
                __builtin_bit_cast(bf16x8, kf[t][0]), qf[0], st[t], 0, 0, 0);
            st[t] = __builtin_amdgcn_mfma_f32_16x16x32_bf16(
                __builtin_bit_cast(bf16x8, kf[t][1]), qf[1], st[t], 0, 0, 0);
        }
        // column (per-q) max over this 32-k tile
        float tm = st[0][0];
#pragma unroll
        for (int r = 1; r < 4; ++r) tm = fmaxf(tm, st[0][r]);
#pragma unroll
        for (int r = 0; r < 4; ++r) tm = fmaxf(tm, st[1][r]);
        tm = fmaxf(tm, __shfl_xor(tm, 16));
        tm = fmaxf(tm, __shfl_xor(tm, 32));
        float mn   = fmaxf(m_run, tm);
        float corr = __expf(m_run - mn);
        m_run = mn;

        float p[2][4];
        float ts = 0.f;
#pragma unroll
        for (int t = 0; t < 2; ++t)
#pragma unroll
            for (int r = 0; r < 4; ++r) {
                p[t][r] = __expf(st[t][r] - mn);
                ts += p[t][r];
            }
        ts += __shfl_xor(ts, 16);
        ts += __shfl_xor(ts, 32);
        l_run = l_run * corr + ts;  // denominator: pre-dropout

        // dropout on P only
#pragma unroll
        for (int t = 0; t < 2; ++t)
#pragma unroll
            for (int r = 0; r < 4; ++r)
                p[t][r] = (mk[t][r] > 0.1f) ? p[t][r] * INV_KEEP : 0.f;

        // rescale accumulator: corr lives at q=c; acc rows are q=4g+r
        float cr[4];
#pragma unroll
        for (int r = 0; r < 4; ++r) cr[r] = __shfl(corr, 4 * g + r);
#pragma unroll
        for (int vb = 0; vb < 4; ++vb)
#pragma unroll
            for (int r = 0; r < 4; ++r) acc[vb][r] *= cr[r];

        // P relayout: lane (g,c) needs P[c][k0+8g+jj], jj=0..7 as bf16x8
        u32 A0 = pk2(p[0][0], p[0][1]), A1 = pk2(p[0][2], p[0][3]);
        u32 B0 = pk2(p[1][0], p[1][1]), B1 = pk2(p[1][2], p[1][3]);
        int sA = ((lane & 16) << 1) + c;  // 32*(g&1)+c
        int sB = sA + 16;
        u32 a0A = __shfl(A0, sA), a1A = __shfl(A1, sA);
        u32 a0B = __shfl(A0, sB), a1B = __shfl(A1, sB);
        u32 b0A = __shfl(B0, sA), b1A = __shfl(B1, sA);
        u32 b0B = __shfl(B0, sB), b1B = __shfl(B1, sB);
        bool hi = (lane & 32) != 0;  // g>=2 -> use t=1 words
        u32x4 wp;
        wp[0] = hi ? b0A : a0A;
        wp[1] = hi ? b1A : a1A;
        wp[2] = hi ? b0B : a0B;
        wp[3] = hi ? b1B : a1B;
        bf16x8 pf = __builtin_bit_cast(bf16x8, wp);

        // PV: O[q][v] tiles, row = q = 4g+r, col = v = vb*16 + c
#pragma unroll
        for (int vb = 0; vb < 4; ++vb)
            acc[vb] = __builtin_amdgcn_mfma_f32_16x16x32_bf16(
                pf, __builtin_bit_cast(bf16x8, vf[vb]), acc[vb], 0, 0, 0);
    };

    u32x4 kfA[2][2], vfA[4]; f4 mkA[2];
    u32x4 kfB[2][2], vfB[4]; f4 mkB[2];
    load_tile(0, kfA, vfA, mkA);
    for (int kt = 0; kt < 64; kt += 2) {
        load_tile((kt + 1) * 32, kfB, vfB, mkB);
        compute_tile(kfA, vfA, mkA);
        if (kt + 2 < 64) load_tile((kt + 2) * 32, kfA, vfA, mkA);
        compute_tile(kfB, vfB, mkB);
    }

    // epilogue: divide by l (per q), store f32
    float li[4];
#pragma unroll
    for (int r = 0; r < 4; ++r) li[r] = 1.f / __shfl(l_run, 4 * g + r);
    float* op = out + ((size_t)(b * SQ_ + q0 + 4 * g)) * DV_ + c;
#pragma unroll
    for (int vb = 0; vb < 4; ++vb)
#pragma unroll
        for (int r = 0; r < 4; ++r)
            __builtin_nontemporal_store(acc[vb][r] * li[r], op + (size_t)r * DV_ + vb * 16);
}

extern "C" void kernel_launch(void* const* d_in, const int* in_sizes, int n_in,
                              void* d_out, int out_size, void* d_ws, size_t ws_size,
                              hipStream_t stream) {
    const float* Q = (const float*)d_in[0];
    const float* K = (const float*)d_in[1];
    const float* V = (const float*)d_in[2];
    const float* M = (const float*)d_in[3];
    float* out = (float*)d_out;

    unsigned short* Kb = (unsigned short*)d_ws;                  // 4 MB
    unsigned short* Vt = Kb + (size_t)B_ * SK_ * D_;             // 4 MB

    // K: 16*2048*64 = 2,097,152 elems; 4/thread -> 2048 blocks
    cast_bf16_k<<<2048, 256, 0, stream>>>(K, Kb);
    transpose_v<<<512, 256, 0, stream>>>(V, Vt);
    attn_main<<<512, 256, 0, stream>>>(Q, Kb, Vt, M, out);
}

// Round 2
// 174.552 us; speedup vs baseline: 1.0022x; 1.0022x over previous
//
#include <hip/hip_runtime.h>
#include <hip/hip_bf16.h>

#define B_ 16
#define SQ_ 2048
#define SK_ 2048
#define D_ 64
#define DV_ 64
#define INV_KEEP 1.1111111f  /* 1/(1-0.1) */

typedef float f4 __attribute__((ext_vector_type(4)));
typedef __bf16 bf16x8 __attribute__((ext_vector_type(8)));
typedef unsigned int u32;
typedef unsigned int u32x4 __attribute__((ext_vector_type(4)));
typedef unsigned short u16x4 __attribute__((ext_vector_type(4)));

// manual f32 -> bf16 RNE (branchless, no NaN inputs here)
static __device__ __forceinline__ unsigned short bf16u(float f) {
    u32 u = __builtin_bit_cast(u32, f);
    u += 0x7fffu + ((u >> 16) & 1u);
    return (unsigned short)(u >> 16);
}
static __device__ __forceinline__ u32 pk2(float lo, float hi) {
    return (u32)bf16u(lo) | ((u32)bf16u(hi) << 16);
}

// ---------------- prep kernel 1: K f32 -> bf16 row-major ----------------
__global__ __launch_bounds__(256) void cast_bf16_k(const float* __restrict__ X,
                                                   unsigned short* __restrict__ Y) {
    size_t i = ((size_t)blockIdx.x * 256 + threadIdx.x) * 4;
    f4 x = *(const f4*)(X + i);
    u16x4 u;
    u.x = bf16u(x.x); u.y = bf16u(x.y); u.z = bf16u(x.z); u.w = bf16u(x.w);
    *(u16x4*)(Y + i) = u;
}

// ---------------- prep kernel 2: V f32 [b][k][v] -> bf16 Vt [b][v][k] ----------------
__global__ __launch_bounds__(256) void transpose_v(const float* __restrict__ V,
                                                   unsigned short* __restrict__ Vt) {
    __shared__ float tile[64][68];
    int b  = blockIdx.x >> 5;
    int k0 = (blockIdx.x & 31) << 6;
    int t  = threadIdx.x;
    int kk = t >> 4, v4 = (t & 15) * 4;
#pragma unroll
    for (int i = 0; i < 4; ++i) {
        f4 x = *(const f4*)(V + ((size_t)(b * SK_ + k0 + kk + i * 16)) * DV_ + v4);
        *(f4*)&tile[kk + i * 16][v4] = x;
    }
    __syncthreads();
    int v = t >> 2, kc = (t & 3) << 4;
    unsigned short* dst = Vt + ((size_t)(b * DV_ + v)) * SK_ + k0 + kc;
#pragma unroll
    for (int j4 = 0; j4 < 4; ++j4) {
        u16x4 u;
        u.x = bf16u(tile[kc + j4 * 4 + 0][v]);
        u.y = bf16u(tile[kc + j4 * 4 + 1][v]);
        u.z = bf16u(tile[kc + j4 * 4 + 2][v]);
        u.w = bf16u(tile[kc + j4 * 4 + 3][v]);
        *(u16x4*)(dst + j4 * 4) = u;
    }
}

// ---------------- main fused attention kernel ----------------
// 1 wave = 16 q-rows x (SK_/SPLIT) k. Swapped QK^T (S^T = K·Q^T), online
// softmax, dropout, PV. SPLIT>1: write unnormalized partial (acc, m, l).
template <int SPLIT>
__global__ __launch_bounds__(256) void attn_main(const float* __restrict__ Q,
                                                 const unsigned short* __restrict__ Kb,
                                                 const unsigned short* __restrict__ Vt,
                                                 const float* __restrict__ mask,
                                                 float* __restrict__ out,
                                                 float* __restrict__ accP,
                                                 float* __restrict__ mlP) {
    constexpr int NT32 = SK_ / SPLIT / 32;   // 32-wide k tiles per wave
    constexpr int NB = 512 * SPLIT;          // total blocks
    // XCD swizzle: each XCD gets NB/8 contiguous blocks (= 2 batches of K/V)
    int bswz = (blockIdx.x & 7) * (NB / 8) + (blockIdx.x >> 3);
    int wid  = threadIdx.x >> 6;
    int split = bswz & (SPLIT - 1);
    int strip = (bswz / SPLIT) * 4 + wid;    // q-strip id in [0, 2048)
    int b  = strip >> 7;
    int q0 = (strip & 127) << 4;
    int kb = split * (SK_ / SPLIT);
    int lane = threadIdx.x & 63;
    int g = lane >> 4, c = lane & 15;

    // Q fragments (B-operand of swapped QK^T): lane reads Q[q0+c][h*32+8g .. +8], scale 1/8 folded
    bf16x8 qf[2];
    {
        const float* qp = Q + ((size_t)(b * SQ_ + q0 + c)) * D_ + 8 * g;
#pragma unroll
        for (int h = 0; h < 2; ++h) {
            f4 a  = *(const f4*)(qp + h * 32);
            f4 bq = *(const f4*)(qp + h * 32 + 4);
            u32x4 wq;
            wq[0] = pk2(a.x * 0.125f, a.y * 0.125f);
            wq[1] = pk2(a.z * 0.125f, a.w * 0.125f);
            wq[2] = pk2(bq.x * 0.125f, bq.y * 0.125f);
            wq[3] = pk2(bq.z * 0.125f, bq.w * 0.125f);
            qf[h] = __builtin_bit_cast(bf16x8, wq);
        }
    }

    const unsigned short* kbase = Kb + ((size_t)(b * SK_ + kb + c)) * D_ + 8 * g;
    const unsigned short* vbase = Vt + ((size_t)(b * DV_ + c)) * SK_ + kb + 8 * g;
    const float* mbase = mask + ((size_t)(b * SQ_ + q0 + c)) * SK_ + kb + 4 * g;

    f4 acc[4];
#pragma unroll
    for (int vb = 0; vb < 4; ++vb) acc[vb] = (f4){0.f, 0.f, 0.f, 0.f};
    float m_run = -__builtin_inff();
    float l_run = 0.f;

    auto load_tile = [&](int k32, u32x4 (&kf)[2][2], u32x4 (&vf)[4], f4 (&mk)[2]) {
#pragma unroll
        for (int t = 0; t < 2; ++t)
#pragma unroll
            for (int h = 0; h < 2; ++h)
                kf[t][h] = *(const u32x4*)(kbase + (size_t)(k32 + 16 * t) * D_ + 32 * h);
#pragma unroll
        for (int vb = 0; vb < 4; ++vb)
            vf[vb] = *(const u32x4*)(vbase + (size_t)vb * 16 * SK_ + k32);
#pragma unroll
        for (int t = 0; t < 2; ++t)
            mk[t] = *(const f4*)(mbase + k32 + 16 * t);   // plain load: let L3 keep it
    };

    auto compute_tile = [&](u32x4 (&kf)[2][2], u32x4 (&vf)[4], f4 (&mk)[2]) {
        // QK^T: S^T tiles [16k][16q], row = k_local = 4g+r (+16t), col = q = c
        f4 st[2];
#pragma unroll
        for (int t = 0; t < 2; ++t) {
            st[t] = (f4){0.f, 0.f, 0.f, 0.f};
            st[t] = __builtin_amdgcn_mfma_f32_16x16x32_bf16(
                __builtin_bit_cast(bf16x8, kf[t][0]), qf[0], st[t], 0, 0, 0);
            st[t] = __builtin_amdgcn_mfma_f32_16x16x32_bf16(
                __builtin_bit_cast(bf16x8, kf[t][1]), qf[1], st[t], 0, 0, 0);
        }
        // column (per-q) max over this 32-k tile
        float tm = st[0][0];
#pragma unroll
        for (int r = 1; r < 4; ++r) tm = fmaxf(tm, st[0][r]);
#pragma unroll
        for (int r = 0; r < 4; ++r) tm = fmaxf(tm, st[1][r]);
        tm = fmaxf(tm, __shfl_xor(tm, 16));
        tm = fmaxf(tm, __shfl_xor(tm, 32));

        bool noup = __all(tm <= m_run);
        float mn;
        if (noup) {
            mn = m_run;  // skip rescale entirely (exact: corr == 1)
        } else {
            mn = fmaxf(m_run, tm);
            float corr = __expf(m_run - mn);
            m_run = mn;
            float cr[4];
#pragma unroll
            for (int r = 0; r < 4; ++r) cr[r] = __shfl(corr, 4 * g + r);
#pragma unroll
            for (int vb = 0; vb < 4; ++vb)
#pragma unroll
                for (int r = 0; r < 4; ++r) acc[vb][r] *= cr[r];
            l_run *= corr;
        }

        float p[2][4];
        float ts = 0.f;
#pragma unroll
        for (int t = 0; t < 2; ++t)
#pragma unroll
            for (int r = 0; r < 4; ++r) {
                p[t][r] = __expf(st[t][r] - mn);
                ts += p[t][r];
            }
        ts += __shfl_xor(ts, 16);
        ts += __shfl_xor(ts, 32);
        l_run += ts;  // denominator: pre-dropout

        // dropout on P only
#pragma unroll
        for (int t = 0; t < 2; ++t)
#pragma unroll
            for (int r = 0; r < 4; ++r)
                p[t][r] = (mk[t][r] > 0.1f) ? p[t][r] * INV_KEEP : 0.f;

        // P relayout: lane (g,c) needs P[c][k0+8g+jj], jj=0..7 as bf16x8
        u32 A0 = pk2(p[0][0], p[0][1]), A1 = pk2(p[0][2], p[0][3]);
        u32 B0 = pk2(p[1][0], p[1][1]), B1 = pk2(p[1][2], p[1][3]);
        int sA = ((lane & 16) << 1) + c;  // 32*(g&1)+c
        int sB = sA + 16;
        u32 a0A = __shfl(A0, sA), a1A = __shfl(A1, sA);
        u32 a0B = __shfl(A0, sB), a1B = __shfl(A1, sB);
        u32 b0A = __shfl(B0, sA), b1A = __shfl(B1, sA);
        u32 b0B = __shfl(B0, sB), b1B = __shfl(B1, sB);
        bool hi = (lane & 32) != 0;  // g>=2 -> use t=1 words
        u32x4 wp;
        wp[0] = hi ? b0A : a0A;
        wp[1] = hi ? b1A : a1A;
        wp[2] = hi ? b0B : a0B;
        wp[3] = hi ? b1B : a1B;
        bf16x8 pf = __builtin_bit_cast(bf16x8, wp);

        // PV: O[q][v] tiles, row = q = 4g+r, col = v = vb*16 + c
#pragma unroll
        for (int vb = 0; vb < 4; ++vb)
            acc[vb] = __builtin_amdgcn_mfma_f32_16x16x32_bf16(
                pf, __builtin_bit_cast(bf16x8, vf[vb]), acc[vb], 0, 0, 0);
    };

    u32x4 kfA[2][2], vfA[4]; f4 mkA[2];
    u32x4 kfB[2][2], vfB[4]; f4 mkB[2];
    load_tile(0, kfA, vfA, mkA);
    for (int kt = 0; kt < NT32; kt += 2) {
        load_tile((kt + 1) * 32, kfB, vfB, mkB);
        compute_tile(kfA, vfA, mkA);
        if (kt + 2 < NT32) load_tile((kt + 2) * 32, kfA, vfA, mkA);
        compute_tile(kfB, vfB, mkB);
    }

    if constexpr (SPLIT == 1) {
        // epilogue: divide by l (per q), store f32
        float li[4];
#pragma unroll
        for (int r = 0; r < 4; ++r) li[r] = 1.f / __shfl(l_run, 4 * g + r);
        float* op = out + ((size_t)(b * SQ_ + q0 + 4 * g)) * DV_ + c;
#pragma unroll
        for (int vb = 0; vb < 4; ++vb)
#pragma unroll
            for (int r = 0; r < 4; ++r)
                __builtin_nontemporal_store(acc[vb][r] * li[r], op + (size_t)r * DV_ + vb * 16);
    } else {
        // write unnormalized partial acc + (m, l)
        float* ap = accP + (((size_t)strip * SPLIT + split) * 16 + 4 * g) * 64 + c;
#pragma unroll
        for (int vb = 0; vb < 4; ++vb)
#pragma unroll
            for (int r = 0; r < 4; ++r)
                ap[(size_t)r * 64 + vb * 16] = acc[vb][r];
        if (g == 0) {
            float* mp = mlP + (((size_t)strip * SPLIT + split) * 16 + c) * 2;
            mp[0] = m_run;
            mp[1] = l_run;
        }
    }
}

// ---------------- combine kernel (SPLIT=4 path) ----------------
__global__ __launch_bounds__(256) void attn_combine(const float* __restrict__ accP,
                                                    const float* __restrict__ mlP,
                                                    float* __restrict__ out) {
    int strip = blockIdx.x;
    int q  = threadIdx.x >> 4;
    int v0 = (threadIdx.x & 15) << 2;
    const float* mp = mlP + (size_t)strip * 128 + q * 2;
    float m[4], l[4];
#pragma unroll
    for (int i = 0; i < 4; ++i) { m[i] = mp[i * 32]; l[i] = mp[i * 32 + 1]; }
    float M = fmaxf(fmaxf(m[0], m[1]), fmaxf(m[2], m[3]));
    const float* ap = accP + (size_t)strip * 4096 + q * 64 + v0;
    float L = 0.f;
    f4 o = (f4){0.f, 0.f, 0.f, 0.f};
#pragma unroll
    for (int i = 0; i < 4; ++i) {
        float w = __expf(m[i] - M);
        L += l[i] * w;
        f4 a = *(const f4*)(ap + i * 1024);
        o += a * w;
    }
    o *= (1.f / L);
    int b  = strip >> 7;
    int q0 = (strip & 127) << 4;
    __builtin_nontemporal_store(o, (f4*)(out + ((size_t)(b * SQ_ + q0 + q)) * DV_ + v0));
}

extern "C" void kernel_launch(void* const* d_in, const int* in_sizes, int n_in,
                              void* d_out, int out_size, void* d_ws, size_t ws_size,
                              hipStream_t stream) {
    const float* Q = (const float*)d_in[0];
    const float* K = (const float*)d_in[1];
    const float* V = (const float*)d_in[2];
    const float* M = (const float*)d_in[3];
    float* out = (float*)d_out;

    unsigned short* Kb = (unsigned short*)d_ws;                  // 4 MB
    unsigned short* Vt = Kb + (size_t)B_ * SK_ * D_;             // 4 MB
    float* accP = (float*)((char*)d_ws + (size_t)16 * 1024 * 1024);   // 32 MB
    float* mlP  = accP + (size_t)2048 * 4 * 16 * 64;                  // 1 MB

    const size_t need = (size_t)16 * 1024 * 1024 + (size_t)2048 * 4 * 16 * 64 * 4
                      + (size_t)2048 * 4 * 16 * 2 * 4;

    cast_bf16_k<<<2048, 256, 0, stream>>>(K, Kb);
    transpose_v<<<512, 256, 0, stream>>>(V, Vt);
    if (ws_size >= need) {
        attn_main<4><<<2048, 256, 0, stream>>>(Q, Kb, Vt, M, out, accP, mlP);
        attn_combine<<<2048, 256, 0, stream>>>(accP, mlP, out);
    } else {
        attn_main<1><<<512, 256, 0, stream>>>(Q, Kb, Vt, M, out, nullptr, nullptr);
    }
}